// Round 1
// baseline (3624.369 us; speedup 1.0000x reference)
//
#include <hip/hip_runtime.h>

// LSTM scan, B=64, T=16384, H=32, I=O=1, fp32.
// ONE WAVE PER BATCH (64 blocks x 64 threads). Pure latency problem: wall
// time = T x per-step dependence-chain length (~480 cyc/step in round 4).
//
// Round-5: chain surgery.
//  - Matvec: 4 independent f2 accumulator chains per gate (depth 16 -> 4)
//    + 3-level tree reduce.
//  - exp2 argument scales folded into PRE-SCALED weights/biases; cell state
//    tracked in scaled space C = -2*log2(e)*c. Every transcendental on the
//    serial chain is now bare exp2 -> add -> rcp (no leading multiply).
//  - h = o*tanh(c) = fma(sig(2c), 2o, -o); 2o,-o computed off-chain.
//  - A-lane p = KT*i*tanh(g) = fma(r2, 2KT*i, -KT*i); u,v on the parallel
//    a1 chain.
//  - Epilogue linear layer: 4-way tree instead of a 32-deep fma chain.
//
// Lane mapping unchanged (validated in round 4): j = lane&31, half = lane>>5.
//   A-lanes (half=0): gates i (row j)    and g (row 64+j)
//   B-lanes (half=1): gates f (row 32+j) and o (row 96+j)
// B-lanes hold the real C,h. A-lanes compute bounded garbage: their q is
// KT*f*o in (KT,0) and a1=i in (0,1), so C_A stays negative and finite;
// h_A = r2*(2*sg-1) in (-1,1).
// Cross-half exchange: permlane32_swap builtin + XOR identity (orientation-
// independent, known-good from round 4).

#define HID 32
#define CHUNK 32

typedef float f2 __attribute__((ext_vector_type(2)));
typedef float f4 __attribute__((ext_vector_type(4)));
typedef unsigned int u32x2 __attribute__((ext_vector_type(2)));

#if defined(__has_builtin)
#if __has_builtin(__builtin_amdgcn_permlane32_swap)
#define HAVE_PLSWAP 1
#endif
#endif

__device__ __forceinline__ float rl(float v, int lane) {
    return __int_as_float(__builtin_amdgcn_readlane(__float_as_int(v), lane));
}

// Exchange p across wave halves: every lane gets the other half's p
// (for its own j). Exact XOR recombination, orientation-independent.
__device__ __forceinline__ float cross_half(float p) {
#ifdef HAVE_PLSWAP
    const unsigned pu = __float_as_uint(p);
    u32x2 r = __builtin_amdgcn_permlane32_swap(pu, pu, false, false);
    return __uint_as_float(r[0] ^ r[1] ^ pu);
#else
    return __shfl_xor(p, 32, 64);
#endif
}

__global__ __launch_bounds__(64, 1)
void lstm_wave_scan(const float* __restrict__ x,
                    const float* __restrict__ W_ih,
                    const float* __restrict__ W_hh,
                    const float* __restrict__ b_ih,
                    const float* __restrict__ b_hh,
                    const float* __restrict__ W_lin,
                    const float* __restrict__ b_lin,
                    float* __restrict__ out,
                    int T) {
    __shared__ float h_hist[CHUNK][65];   // row stride 65: epilogue conflict-free

    const int lane = threadIdx.x;
    const int j    = lane & 31;
    const int half = lane >> 5;
    const int b    = blockIdx.x;

    const int row1 = j + (half << 5);         // A: i-row j     B: f-row 32+j
    const int row2 = 64 + j + (half << 5);    // A: g-row 64+j  B: o-row 96+j

    const float K1 = -1.44269504088896340736f;   // -log2(e): sigmoid arg scale
    const float KT = -2.88539008177792681472f;   // -2*log2(e): tanh-as-sigmoid
    const float K2 = half ? K1 : KT;             // gate2: B=o (sig), A=g (tanh)
    const float cu = half ? KT : 2.0f * KT;      // p = fma(r2, cu*a1, cv*a1)
    const float cv = half ? 0.0f : -KT;          //   (p lives in C-space)

    // Load + pre-scale weights (once; rounding adds ~1e-7 rel, negligible).
    f2 w1[16], w2[16];
    {
        const f4* R1 = (const f4*)(W_hh + row1 * HID);
        const f4* R2 = (const f4*)(W_hh + row2 * HID);
#pragma unroll
        for (int m = 0; m < 8; ++m) {
            f4 v1 = R1[m];
            w1[2*m]   = f2{v1.x * K1, v1.y * K1};
            w1[2*m+1] = f2{v1.z * K1, v1.w * K1};
            f4 v2 = R2[m];
            w2[2*m]   = f2{v2.x * K2, v2.y * K2};
            w2[2*m+1] = f2{v2.z * K2, v2.w * K2};
        }
    }
    const float wih1 = W_ih[row1] * K1;
    const float bb1  = (b_ih[row1] + b_hh[row1]) * K1;
    const float wih2 = W_ih[row2] * K2;
    const float bb2  = (b_ih[row2] + b_hh[row2]) * K2;
    const float blin = b_lin[0];

    float C = 0.0f;     // B-lanes: KT * cell state  (A-lanes: bounded garbage)
    float h = 0.0f;     // B-lanes: hidden state h_{t-1}

    const float* xb = x   + (size_t)b * T;
    float*       ob = out + (size_t)b * T;

    float xv = xb[j];

    for (int t0 = 0; t0 < T; t0 += CHUNK) {
        int t0n = t0 + CHUNK; if (t0n >= T) t0n = 0;
        float xv_next = xb[t0n + j];

#pragma unroll 8
        for (int tt = 0; tt < CHUNK; ++tt) {
            const float sx = rl(xv, tt);  // wave-uniform x_t

            // 4 independent chains per gate row: depth 4, then tree-reduce.
            f2 acc1[4], acc2[4];
            acc1[0] = f2{__builtin_fmaf(sx, wih1, bb1), 0.0f};
            acc2[0] = f2{__builtin_fmaf(sx, wih2, bb2), 0.0f};
#pragma unroll
            for (int k = 1; k < 4; ++k) {
                acc1[k] = f2{0.0f, 0.0f};
                acc2[k] = f2{0.0f, 0.0f};
            }

#pragma unroll
            for (int g = 0; g < 4; ++g) {
#pragma unroll
                for (int k = 0; k < 4; ++k) {
                    const int mp = 4*g + k;
                    f2 hm = f2{rl(h, 32 + 2*mp), rl(h, 32 + 2*mp + 1)};
                    acc1[k] = __builtin_elementwise_fma(w1[mp], hm, acc1[k]);
                    acc2[k] = __builtin_elementwise_fma(w2[mp], hm, acc2[k]);
                }
            }
            f2 s1 = (acc1[0] + acc1[1]) + (acc1[2] + acc1[3]);
            f2 s2 = (acc2[0] + acc2[1]) + (acc2[2] + acc2[3]);
            const float m1 = s1.x + s1.y;   // A: K1*i-pre   B: K1*f-pre
            const float m2 = s2.x + s2.y;   // A: KT*g-pre   B: K1*o-pre

            // bare exp2 -> add -> rcp (scales pre-folded into m1/m2)
            const float a1 = __builtin_amdgcn_rcpf(1.0f + __builtin_amdgcn_exp2f(m1));
            const float r2 = __builtin_amdgcn_rcpf(1.0f + __builtin_amdgcn_exp2f(m2));

            const float uu = cu * a1;       // off the r2 chain (parallel)
            const float vv = cv * a1;
            const float o2 = r2 + r2;       // off the C chain
            const float on = -r2;

            const float p = __builtin_fmaf(r2, uu, vv);
                                            // A: KT*i*tanh(g)   B: KT*f*o
            const float q = cross_half(p);  // A: KT*f*o         B: KT*i*tanh(g)

            C = __builtin_fmaf(a1, C, q);   // B: KT*(f*c + i*g~)
            const float sg = __builtin_amdgcn_rcpf(1.0f + __builtin_amdgcn_exp2f(C));
                                            // B: sigmoid(2c)
            h = __builtin_fmaf(sg, o2, on); // B: o*(2*sig(2c)-1) = o*tanh(c)

            h_hist[tt][lane] = h;           // cols 32..63 hold the real h
        }

        // ---- epilogue: out[b][t0+t'] = x + W_lin . h_t' + b_lin, t' = j
        {
            float fa = 0.0f, fb = 0.0f, fc = 0.0f, fd = 0.0f;
#pragma unroll
            for (int k = 0; k < 8; ++k) {
                fa = __builtin_fmaf(W_lin[4*k+0], h_hist[j][32 + 4*k+0], fa);
                fb = __builtin_fmaf(W_lin[4*k+1], h_hist[j][32 + 4*k+1], fb);
                fc = __builtin_fmaf(W_lin[4*k+2], h_hist[j][32 + 4*k+2], fc);
                fd = __builtin_fmaf(W_lin[4*k+3], h_hist[j][32 + 4*k+3], fd);
            }
            if (half == 0)
                ob[t0 + j] = xv + ((fa + fb) + (fc + fd)) + blin;
        }

        xv = xv_next;
    }
}

extern "C" void kernel_launch(void* const* d_in, const int* in_sizes, int n_in,
                              void* d_out, int out_size, void* d_ws, size_t ws_size,
                              hipStream_t stream) {
    const float* x     = (const float*)d_in[0];
    const float* W_ih  = (const float*)d_in[1];
    const float* W_hh  = (const float*)d_in[2];
    const float* b_ih  = (const float*)d_in[3];
    const float* b_hh  = (const float*)d_in[4];
    const float* W_lin = (const float*)d_in[5];
    const float* b_lin = (const float*)d_in[6];
    float* out = (float*)d_out;

    const int B = 64;
    const int T = in_sizes[0] / B;   // 16384

    dim3 grid(B);
    dim3 block(64);
    lstm_wave_scan<<<grid, block, 0, stream>>>(x, W_ih, W_hh, b_ih, b_hh,
                                               W_lin, b_lin, out, T);
}

// Round 2
// 3445.832 us; speedup vs baseline: 1.0518x; 1.0518x over previous
//
#include <hip/hip_runtime.h>

// LSTM scan, B=64, T=16384, H=32, I=O=1, fp32.
// ONE WAVE PER BATCH (64 blocks x 64 threads). Pure latency problem: wall
// time = T x per-step serial work of one wave.
//
// Round-6: weight-residency fix.
//   Round-4/5 post-mortem: VGPR_Count stayed 60-64 while per-lane weight
//   state alone is 64 floats -> the compiler never kept W_hh in registers;
//   it re-fetched weights inside the loop (remat/sink), putting ~300 cyc of
//   memory-wait stalls on every one of the 16384 serial steps. Round 5's
//   extra accumulators increased the overflow and regressed.
//   Fix: pin all 32 f2 weights (+ the 4 hot scalars) with an opaque-def
//   asm ("+v") after loading. The value can no longer be rematerialized
//   from memory, and __launch_bounds__(64,1) gives a 512-VGPR budget, so
//   the allocator keeps them resident.
//   Matvec reverted to round-4's 2-chain pk-FMA form (latency-matched, no
//   bubbles); round-5 algebraic chain shortening kept:
//    - pre-scaled weights; cell state tracked as C = -2*log2(e)*c, so every
//      transcendental is bare exp2 -> add -> rcp;
//    - h = o*tanh(c) = fma(sig(2c), 2o, -o), 2o/-o computed off-chain;
//    - A-lane p = KT*i*tanh(g) = fma(r2, 2KT*i, -KT*i), both products on
//      the parallel a1 chain.
//
// Lane mapping (validated round 4): j = lane&31, half = lane>>5.
//   A-lanes (half=0): gates i (row j)    and g (row 64+j)
//   B-lanes (half=1): gates f (row 32+j) and o (row 96+j)
// B-lanes hold the real C,h. A-lanes compute bounded garbage: q_A = KT*f*o
// in (KT,0), a1=i in (0,1) -> C_A stays negative and finite; h_A in (-1,1).
// Cross-half exchange: permlane32_swap builtin + XOR identity (orientation-
// independent, known-good).

#define HID 32
#define CHUNK 32

typedef float f2 __attribute__((ext_vector_type(2)));
typedef float f4 __attribute__((ext_vector_type(4)));
typedef unsigned int u32x2 __attribute__((ext_vector_type(2)));

#if defined(__has_builtin)
#if __has_builtin(__builtin_amdgcn_permlane32_swap)
#define HAVE_PLSWAP 1
#endif
#endif

// Opaque def: forbids rematerialization of x from memory, forcing VGPR
// residency (allocator has a 512-VGPR budget at 1 wave/EU).
#define PIN(x) asm volatile("" : "+v"(x))

__device__ __forceinline__ float rl(float v, int lane) {
    return __int_as_float(__builtin_amdgcn_readlane(__float_as_int(v), lane));
}

// Exchange p across wave halves: every lane gets the other half's p
// (for its own j). Exact XOR recombination, orientation-independent.
__device__ __forceinline__ float cross_half(float p) {
#ifdef HAVE_PLSWAP
    const unsigned pu = __float_as_uint(p);
    u32x2 r = __builtin_amdgcn_permlane32_swap(pu, pu, false, false);
    return __uint_as_float(r[0] ^ r[1] ^ pu);
#else
    return __shfl_xor(p, 32, 64);
#endif
}

__global__ __launch_bounds__(64, 1)
void lstm_wave_scan(const float* __restrict__ x,
                    const float* __restrict__ W_ih,
                    const float* __restrict__ W_hh,
                    const float* __restrict__ b_ih,
                    const float* __restrict__ b_hh,
                    const float* __restrict__ W_lin,
                    const float* __restrict__ b_lin,
                    float* __restrict__ out,
                    int T) {
    __shared__ float h_hist[CHUNK][65];   // row stride 65: epilogue conflict-free

    const int lane = threadIdx.x;
    const int j    = lane & 31;
    const int half = lane >> 5;
    const int b    = blockIdx.x;

    const int row1 = j + (half << 5);         // A: i-row j     B: f-row 32+j
    const int row2 = 64 + j + (half << 5);    // A: g-row 64+j  B: o-row 96+j

    const float K1 = -1.44269504088896340736f;   // -log2(e): sigmoid arg scale
    const float KT = -2.88539008177792681472f;   // -2*log2(e): tanh-as-sigmoid
    const float K2 = half ? K1 : KT;             // gate2: B=o (sig), A=g (tanh)
    const float cu = half ? KT : 2.0f * KT;      // p = fma(r2, cu*a1, cv*a1)
    const float cv = half ? 0.0f : -KT;          //   (p lives in C-space)

    // Load + pre-scale weights (once), then PIN each in a VGPR.
    f2 w1[16], w2[16];
    {
        const f4* R1 = (const f4*)(W_hh + row1 * HID);
        const f4* R2 = (const f4*)(W_hh + row2 * HID);
#pragma unroll
        for (int m = 0; m < 8; ++m) {
            f4 v1 = R1[m];
            w1[2*m]   = f2{v1.x * K1, v1.y * K1};
            w1[2*m+1] = f2{v1.z * K1, v1.w * K1};
            f4 v2 = R2[m];
            w2[2*m]   = f2{v2.x * K2, v2.y * K2};
            w2[2*m+1] = f2{v2.z * K2, v2.w * K2};
            PIN(w1[2*m]); PIN(w1[2*m+1]);
            PIN(w2[2*m]); PIN(w2[2*m+1]);
        }
    }
    float wih1 = W_ih[row1] * K1;
    float bb1  = (b_ih[row1] + b_hh[row1]) * K1;
    float wih2 = W_ih[row2] * K2;
    float bb2  = (b_ih[row2] + b_hh[row2]) * K2;
    PIN(wih1); PIN(bb1); PIN(wih2); PIN(bb2);
    const float blin = b_lin[0];

    float C = 0.0f;     // B-lanes: KT * cell state  (A-lanes: bounded garbage)
    float h = 0.0f;     // B-lanes: hidden state h_{t-1}

    const float* xb = x   + (size_t)b * T;
    float*       ob = out + (size_t)b * T;

    float xv = xb[j];

    for (int t0 = 0; t0 < T; t0 += CHUNK) {
        int t0n = t0 + CHUNK; if (t0n >= T) t0n = 0;
        float xv_next = xb[t0n + j];

#pragma unroll 8
        for (int tt = 0; tt < CHUNK; ++tt) {
            const float sx = rl(xv, tt);  // wave-uniform x_t

            // 2 interleaved pk-FMA chains (round-4 form): 2-cyc issue each,
            // 4-cyc chain advance = FMA latency -> no bubbles.
            f2 acc1 = f2{__builtin_fmaf(sx, wih1, bb1), 0.0f};
            f2 acc2 = f2{__builtin_fmaf(sx, wih2, bb2), 0.0f};
#pragma unroll
            for (int m = 0; m < 16; ++m) {
                f2 hm = f2{rl(h, 32 + 2*m), rl(h, 32 + 2*m + 1)};
                acc1 = __builtin_elementwise_fma(w1[m], hm, acc1);
                acc2 = __builtin_elementwise_fma(w2[m], hm, acc2);
            }
            const float m1 = acc1.x + acc1.y;   // A: K1*i-pre   B: K1*f-pre
            const float m2 = acc2.x + acc2.y;   // A: KT*g-pre   B: K1*o-pre

            // bare exp2 -> add -> rcp (scales pre-folded into m1/m2)
            const float a1 = __builtin_amdgcn_rcpf(1.0f + __builtin_amdgcn_exp2f(m1));
            const float r2 = __builtin_amdgcn_rcpf(1.0f + __builtin_amdgcn_exp2f(m2));

            const float uu = cu * a1;       // off the r2 chain (parallel)
            const float vv = cv * a1;
            const float o2 = r2 + r2;       // off the C chain
            const float on = -r2;

            const float p = __builtin_fmaf(r2, uu, vv);
                                            // A: KT*i*tanh(g)   B: KT*f*o
            const float q = cross_half(p);  // A: KT*f*o         B: KT*i*tanh(g)

            C = __builtin_fmaf(a1, C, q);   // B: KT*(f*c + i*g~)
            const float sg = __builtin_amdgcn_rcpf(1.0f + __builtin_amdgcn_exp2f(C));
                                            // B: sigmoid(2c)
            h = __builtin_fmaf(sg, o2, on); // B: o*(2*sig(2c)-1) = o*tanh(c)

            h_hist[tt][lane] = h;           // cols 32..63 hold the real h
        }

        // ---- epilogue: out[b][t0+t'] = x + W_lin . h_t' + b_lin, t' = j
        {
            float fa = 0.0f, fb = 0.0f, fc = 0.0f, fd = 0.0f;
#pragma unroll
            for (int k = 0; k < 8; ++k) {
                fa = __builtin_fmaf(W_lin[4*k+0], h_hist[j][32 + 4*k+0], fa);
                fb = __builtin_fmaf(W_lin[4*k+1], h_hist[j][32 + 4*k+1], fb);
                fc = __builtin_fmaf(W_lin[4*k+2], h_hist[j][32 + 4*k+2], fc);
                fd = __builtin_fmaf(W_lin[4*k+3], h_hist[j][32 + 4*k+3], fd);
            }
            if (half == 0)
                ob[t0 + j] = xv + ((fa + fb) + (fc + fd)) + blin;
        }

        xv = xv_next;
    }
}

extern "C" void kernel_launch(void* const* d_in, const int* in_sizes, int n_in,
                              void* d_out, int out_size, void* d_ws, size_t ws_size,
                              hipStream_t stream) {
    const float* x     = (const float*)d_in[0];
    const float* W_ih  = (const float*)d_in[1];
    const float* W_hh  = (const float*)d_in[2];
    const float* b_ih  = (const float*)d_in[3];
    const float* b_hh  = (const float*)d_in[4];
    const float* W_lin = (const float*)d_in[5];
    const float* b_lin = (const float*)d_in[6];
    float* out = (float*)d_out;

    const int B = 64;
    const int T = in_sizes[0] / B;   // 16384

    dim3 grid(B);
    dim3 block(64);
    lstm_wave_scan<<<grid, block, 0, stream>>>(x, W_ih, W_hh, b_ih, b_hh,
                                               W_lin, b_lin, out, T);
}